// Round 2
// 1055.395 us; speedup vs baseline: 1.0100x; 1.0100x over previous
//
#include <hip/hip_runtime.h>

// CWTConv2D: x (32,512,512) f32 -> round; k (32,3,3) -> round+clip to {-1,0,1},
// spatially flipped conv (VALID) -> out (32,510,510,32) NHWC f32, +round(bias), relu.
//
// R6 = R5 with the weight-staging bug fixed (R5 staged only 256 of 288 ws[]
// entries -> tap 8 was uninitialized LDS).
//
// R5 idea (unchanged): fill-like contiguous stores. Lane map (f4 = lane&7
// fastest, jg = lane>>3), j = 128*wave + jg + 8*s  =>  every wave store step
// writes ONE contiguous 1 KB nontemporal burst (the 6.2 TB/s fillBuffer
// pattern), instead of R4's 8x128B segments over 16 KB.
// x rows staged in LDS quantized ONCE; weights quantized once per block.

#define BATCH 32
#define H 512
#define W 512
#define NF 32
#define HO 510
#define WO 510

typedef float vfloat4 __attribute__((ext_vector_type(4)));

__global__ __launch_bounds__(256) void cwt_conv_kernel(
    const float* __restrict__ x,
    const float* __restrict__ kw,
    const float* __restrict__ bias,
    float* __restrict__ out)
{
    __shared__ float xs[3][W];    // 6 KB: quantized input rows i..i+2
    __shared__ float ws[9][NF];   // quantized, spatially-flipped weights [tap][filter]
    __shared__ float bs[NF];      // rounded biases

    const int tid = threadIdx.x;
    const int i = blockIdx.x;   // output row 0..509
    const int b = blockIdx.y;

    // --- Stage quantized weights: tap t=(di*3+dj) uses kw[f][2-di][2-dj] = kw[f*9 + 8-t].
    // 288 entries > 256 threads: strided loop (R5 bug: tap 8 was never staged).
    for (int idx = tid; idx < 9 * NF; idx += 256) {
        const int t = idx >> 5;        // tap 0..8
        const int f = idx & 31;        // filter 0..31
        const float v = rintf(kw[f * 9 + (8 - t)]);
        ws[t][f] = fminf(fmaxf(v, -1.0f), 1.0f);
    }
    if (tid < NF) bs[tid] = rintf(bias[tid]);

    // --- Stage x rows i..i+2, rounded once per element (coalesced float4 loads).
    const float* xrow = x + ((size_t)(b * H + i)) * W;
#pragma unroll
    for (int k = 0; k < 2; ++k) {
        const int idx = tid + k * 256;       // 384 float4 units total
        if (idx < 384) {
            const int r  = idx >> 7;         // row 0..2
            const int c4 = idx & 127;        // float4 col
            const float4 v = reinterpret_cast<const float4*>(xrow + (size_t)r * W)[c4];
            float* d = &xs[r][c4 * 4];
            d[0] = rintf(v.x); d[1] = rintf(v.y);
            d[2] = rintf(v.z); d[3] = rintf(v.w);
        }
    }
    __syncthreads();

    // --- Lane map: f4 fastest so wave stores are address-contiguous.
    const int lane = tid & 63;
    const int wv   = tid >> 6;     // wave 0..3: j block [128*wv, 128*wv+127]
    const int f4   = lane & 7;     // filter quad: filters 4*f4..4*f4+3
    const int jg   = lane >> 3;    // 0..7

    float wq[9][4];
#pragma unroll
    for (int t = 0; t < 9; ++t) {
        const float4 w4 = *reinterpret_cast<const float4*>(&ws[t][f4 * 4]);
        wq[t][0] = w4.x; wq[t][1] = w4.y; wq[t][2] = w4.z; wq[t][3] = w4.w;
    }
    float bq[4];
    {
        const float4 b4 = *reinterpret_cast<const float4*>(&bs[f4 * 4]);
        bq[0] = b4.x; bq[1] = b4.y; bq[2] = b4.z; bq[3] = b4.w;
    }

    const int jbase = wv * 128 + jg;
    vfloat4* out4 = reinterpret_cast<vfloat4*>(out);
    // float4-unit index; at step s the wave writes out[b][i][128*wv+8s .. +7][0..31],
    // i.e. lane*16B contiguous -> one 1 KB burst per wave store.
    const int obase = ((b * HO + i) * WO + jbase) * (NF / 4) + f4;

#pragma unroll 4
    for (int s = 0; s < 16; ++s) {
        const int j = jbase + 8 * s;        // up to 511; mask 510/511 (s==15, jg>=6)
        if (j < WO) {
            float a0 = bq[0], a1 = bq[1], a2 = bq[2], a3 = bq[3];
#pragma unroll
            for (int r = 0; r < 3; ++r) {
#pragma unroll
                for (int dj = 0; dj < 3; ++dj) {
                    const float xv = xs[r][j + dj];   // 8-way broadcast, conflict-free
                    const int t = r * 3 + dj;
                    a0 = fmaf(xv, wq[t][0], a0);
                    a1 = fmaf(xv, wq[t][1], a1);
                    a2 = fmaf(xv, wq[t][2], a2);
                    a3 = fmaf(xv, wq[t][3], a3);
                }
            }
            vfloat4 o;
            o.x = fmaxf(a0, 0.0f);
            o.y = fmaxf(a1, 0.0f);
            o.z = fmaxf(a2, 0.0f);
            o.w = fmaxf(a3, 0.0f);
            __builtin_nontemporal_store(o, &out4[obase + s * 8 * (NF / 4)]);
        }
    }
}

extern "C" void kernel_launch(void* const* d_in, const int* in_sizes, int n_in,
                              void* d_out, int out_size, void* d_ws, size_t ws_size,
                              hipStream_t stream) {
    const float* x    = (const float*)d_in[0];
    const float* kw   = (const float*)d_in[1];
    const float* bias = (const float*)d_in[2];
    float* out = (float*)d_out;

    dim3 grid(HO, BATCH);   // 510 x 32 blocks, one output row each
    dim3 block(256);
    cwt_conv_kernel<<<grid, block, 0, stream>>>(x, kw, bias, out);
}